// Round 4
// baseline (158.560 us; speedup 1.0000x reference)
//
#include <hip/hip_runtime.h>

// Problem constants (frozen by the reference)
#define NN 16
#define CC 64
#define HH 128
#define WW 128

#define LDS_STRIDE 72    // bf16 elems per xsT row (144 B; dword stride 36)
#define T3B_STRIDE 132   // bf16 elems per t3b row (264 B, 8B-aligned rows)

typedef __attribute__((ext_vector_type(8))) short short8;   // bf16x8 (4 VGPRs)
typedef __attribute__((ext_vector_type(4))) float floatx4;  // MFMA C/D

__device__ __forceinline__ short f2bf(float f) {
    union { float f; unsigned u; } v; v.f = f;
    unsigned r = v.u + 0x7fffu + ((v.u >> 16) & 1u);
    return (short)(r >> 16);
}
__device__ __forceinline__ unsigned pack2bf(float lo, float hi) {
    // lo -> bits 15:0 (even ci), hi -> bits 31:16 (odd ci), RNE
    union { float f; unsigned u; } a, b; a.f = lo; b.f = hi;
    unsigned ra = a.u + 0x7fffu + ((a.u >> 16) & 1u);
    unsigned rb = b.u + 0x7fffu + ((b.u >> 16) & 1u);
    return (ra >> 16) | (rb & 0xffff0000u);
}
__device__ __forceinline__ float bf2f(unsigned short u) {
    union { unsigned u; float f; } v; v.u = ((unsigned)u) << 16;
    return v.f;
}

// ---------------------------------------------------------------------------
// Kernel 0: w3 (co, ci, 1, 5) fp32 -> Abf[co][kk] bf16, kk = tap*64 + ci.
// ---------------------------------------------------------------------------
__global__ __launch_bounds__(256) void prep_w(const float* __restrict__ w3,
                                              short* __restrict__ Abf) {
    int idx = blockIdx.x * 256 + threadIdx.x;
    if (idx < CC * CC * 5) {
        int tap = idx % 5;
        int ci  = (idx / 5) % CC;
        int co  = idx / (5 * CC);
        Abf[co * 320 + tap * 64 + ci] = f2bf(w3[idx]);
    }
}

// ---------------------------------------------------------------------------
// Fused kernel, one block per (n,h) row. LDS = 19008 B -> 8 blocks/CU.
// Phase 1: stage x row transposed bf16, packed ci-pairs per dword
//          (ds_write_b32, 32 lanes span 32 banks -> conflict-free).
// Phase 2: MFMA GEMM D[co][w] = sum_kk A[co][kk] B[kk][w], kk = tap*64+ci.
// Phase 3: D -> LDS t3b (bf16, aliases dead xsT).
// Phase 4: combine: out = t3 * sum_{j,i} w7[c,3j+i]*max(lhs(i), rhs(j,i)).
// ---------------------------------------------------------------------------
__global__ __launch_bounds__(256, 8) void fused(const float* __restrict__ x,
                                                const short* __restrict__ Abf,
                                                const float* __restrict__ w7,
                                                float* __restrict__ out) {
    __shared__ __align__(16) char smem[132 * LDS_STRIDE * 2];  // 19008 B
    short*    xsT = (short*)smem;      // [132][LDS_STRIDE] bf16, phases 1-2
    unsigned* xsW = (unsigned*)smem;   // dword view, stride 36
    short*    t3b = (short*)smem;      // [CC][T3B_STRIDE] bf16, phases 3-4

    const int nh  = blockIdx.x;
    const int n   = nh >> 7;
    const int h   = nh & (HH - 1);
    const int tid = threadIdx.x;

    // ---- Phase 1: each thread owns ci-pair cp and w-strip wqg*16..+15 ----
    const float* xbase = x + (((size_t)n * CC) * HH + h) * WW;
    {
        const int cp  = tid & 31;       // ci pair: rows 2cp, 2cp+1
        const int wqg = tid >> 5;       // 0..7 -> w = wqg*16 .. +15
        const float* r0 = xbase + (size_t)(2 * cp) * (HH * WW);
        const float* r1 = r0 + HH * WW;
        #pragma unroll
        for (int q = 0; q < 4; ++q) {
            int wq = wqg * 4 + q;
            float4 a = *(const float4*)(r0 + wq * 4);
            float4 b = *(const float4*)(r1 + wq * 4);
            int wp = wq * 4 + 2;
            xsW[(wp + 0) * 36 + cp] = pack2bf(a.x, b.x);
            xsW[(wp + 1) * 36 + cp] = pack2bf(a.y, b.y);
            xsW[(wp + 2) * 36 + cp] = pack2bf(a.z, b.z);
            xsW[(wp + 3) * 36 + cp] = pack2bf(a.w, b.w);
        }
        if (tid < 128) {    // zero pad rows wp in {0,1,130,131}
            int wpi = tid >> 5;
            int wpz = (wpi < 2) ? wpi : 128 + wpi;
            xsW[wpz * 36 + (tid & 31)] = 0u;
        }
    }
    __syncthreads();

    // ---- Phase 2: MFMA ----
    const int W    = tid >> 6;       // wave id -> co-tile
    const int lane = tid & 63;
    const int lm   = lane & 15;
    const int g    = lane >> 4;

    floatx4 acc[8];
    #pragma unroll
    for (int nt = 0; nt < 8; ++nt) acc[nt] = (floatx4){0.f, 0.f, 0.f, 0.f};

    const short* arow = Abf + (W * 16 + lm) * 320;

    for (int ks = 0; ks < 10; ++ks) {
        const int kbase = ks * 32 + g * 8;
        const int tap   = kbase >> 6;
        const int cib   = kbase & 63;

        short8 a = *(const short8*)(arow + kbase);
        #pragma unroll
        for (int nt = 0; nt < 8; ++nt) {
            int wp = nt * 16 + lm + tap;
            short8 b = *(const short8*)&xsT[wp * LDS_STRIDE + cib];
            acc[nt] = __builtin_amdgcn_mfma_f32_16x16x32_bf16(a, b, acc[nt], 0, 0, 0);
        }
    }
    __syncthreads();   // xsT dead; t3b aliases it

    // ---- Phase 3: epilogue to LDS (bf16). Banks: co*66 + w/2 -> 32 banks,
    // lm/lm+1 pairs share a dword (byte-enable) -> conflict-free. ----
    #pragma unroll
    for (int nt = 0; nt < 8; ++nt) {
        #pragma unroll
        for (int r = 0; r < 4; ++r) {
            int co = W * 16 + g * 4 + r;
            t3b[co * T3B_STRIDE + nt * 16 + lm] = f2bf(acc[nt][r]);
        }
    }
    __syncthreads();

    // ---- Phase 4: combine, 4 outputs/thread, 8 iterations ----
    float* orow = out + (((size_t)n * CC) * HH + h) * WW;
    #pragma unroll
    for (int it = 0; it < 8; ++it) {
        const int item = it * 256 + tid;
        const int flat = item * 4;          // c*128 + w0
        const int w0   = flat & (WW - 1);
        const int c    = flat >> 7;
        const float* xb = x + ((size_t)(n * CC + c) * HH) * WW;

        float win[3][12];
        #pragma unroll
        for (int r = 0; r < 3; ++r) {
            int hh = h + r - 1;
            bool hok = (unsigned)hh < HH;
            #pragma unroll
            for (int q = 0; q < 3; ++q) {
                int cb = w0 - 4 + q * 4;
                float4 v = make_float4(0.f, 0.f, 0.f, 0.f);
                if (hok && (unsigned)cb < WW)
                    v = *(const float4*)(xb + hh * WW + cb);
                win[r][q * 4 + 0] = v.x; win[r][q * 4 + 1] = v.y;
                win[r][q * 4 + 2] = v.z; win[r][q * 4 + 3] = v.w;
            }
        }
        // w==0 wrap: rhs cols 125, 127 (j=2 -> col 129 -> 0 via pad).
        float wrap0[3] = {0.f, 0.f, 0.f}, wrap1[3] = {0.f, 0.f, 0.f};
        if (w0 == 0) {
            #pragma unroll
            for (int r = 0; r < 3; ++r) {
                int hh = h + r - 1;
                if ((unsigned)hh < HH) {
                    wrap0[r] = xb[hh * WW + 125];
                    wrap1[r] = xb[hh * WW + 127];
                }
            }
        }
        float wc[9];
        #pragma unroll
        for (int t = 0; t < 9; ++t) wc[t] = w7[c * 9 + t];

        ushort4 tv = *(const ushort4*)&t3b[c * T3B_STRIDE + w0];
        float t3v[4] = {bf2f(tv.x), bf2f(tv.y), bf2f(tv.z), bf2f(tv.w)};

        float res[4];
        #pragma unroll
        for (int e = 0; e < 4; ++e) {
            float a = 0.f;
            #pragma unroll
            for (int j = 0; j < 3; ++j) {
                #pragma unroll
                for (int i = 0; i < 3; ++i) {
                    float lhs = win[1][e + 2 * i + 2];        // col w+2(i-1)
                    float rhs;
                    if (e == 0 && w0 == 0)
                        rhs = (j == 0) ? wrap0[i] : ((j == 1) ? wrap1[i] : 0.f);
                    else
                        rhs = win[i][e + 2 * j + 1];          // col w+2j-3
                    a = fmaf(wc[j * 3 + i], fmaxf(lhs, rhs), a);
                }
            }
            res[e] = a;
        }
        float4 o;
        o.x = res[0] * t3v[0]; o.y = res[1] * t3v[1];
        o.z = res[2] * t3v[2]; o.w = res[3] * t3v[3];
        *(float4*)(orow + (size_t)c * (HH * WW) + w0) = o;
    }
}

extern "C" void kernel_launch(void* const* d_in, const int* in_sizes, int n_in,
                              void* d_out, int out_size, void* d_ws, size_t ws_size,
                              hipStream_t stream) {
    const float* x  = (const float*)d_in[0];
    const float* w3 = (const float*)d_in[1];
    const float* w7 = (const float*)d_in[2];
    float* out = (float*)d_out;

    short* Abf = (short*)d_ws;   // 40 KiB bf16 weights

    prep_w<<<(CC * CC * 5 + 255) / 256, 256, 0, stream>>>(w3, Abf);
    fused<<<NN * HH, 256, 0, stream>>>(x, Abf, w7, out);
}

// Round 5
// 153.954 us; speedup vs baseline: 1.0299x; 1.0299x over previous
//
#include <hip/hip_runtime.h>

// Problem constants (frozen by the reference)
#define NN 16
#define CC 64
#define HH 128
#define WW 128

#define LDS_STRIDE 72    // bf16 elems per xsT row (144 B; dword stride 36)
#define T3B_STRIDE 132   // bf16 elems per t3b row (264 B, 8B-aligned rows)

typedef __attribute__((ext_vector_type(8))) short short8;   // bf16x8 (4 VGPRs)
typedef __attribute__((ext_vector_type(4))) float floatx4;  // MFMA C/D

__device__ __forceinline__ short f2bf(float f) {
    union { float f; unsigned u; } v; v.f = f;
    unsigned r = v.u + 0x7fffu + ((v.u >> 16) & 1u);
    return (short)(r >> 16);
}
__device__ __forceinline__ unsigned pack2bf(float lo, float hi) {
    // lo -> bits 15:0 (even ci), hi -> bits 31:16 (odd ci), RNE
    union { float f; unsigned u; } a, b; a.f = lo; b.f = hi;
    unsigned ra = a.u + 0x7fffu + ((a.u >> 16) & 1u);
    unsigned rb = b.u + 0x7fffu + ((b.u >> 16) & 1u);
    return (ra >> 16) | (rb & 0xffff0000u);
}
__device__ __forceinline__ float bf2f(unsigned short u) {
    union { unsigned u; float f; } v; v.u = ((unsigned)u) << 16;
    return v.f;
}

// ---------------------------------------------------------------------------
// Kernel 0: w3 (co, ci, 1, 5) fp32 -> Abf[co][kk] bf16, kk = tap*64 + ci.
// ---------------------------------------------------------------------------
__global__ __launch_bounds__(256) void prep_w(const float* __restrict__ w3,
                                              short* __restrict__ Abf) {
    int idx = blockIdx.x * 256 + threadIdx.x;
    if (idx < CC * CC * 5) {
        int tap = idx % 5;
        int ci  = (idx / 5) % CC;
        int co  = idx / (5 * CC);
        Abf[co * 320 + tap * 64 + ci] = f2bf(w3[idx]);
    }
}

// ---------------------------------------------------------------------------
// Fused kernel, one block per (n,h) row. LDS = 19008 B.
// __launch_bounds__(256,4): 128 unified regs/thread -> ~96 VGPR + 32 AGPR,
// enough for phase-4 to keep 9 float4 window loads in flight (R4's (256,8)
// cap of 64 regs starved phase 4 of ILP -> latency-bound regression).
// XCD swizzle: nh = (bid&7)*256 + (bid>>3) puts consecutive h on one XCD so
// phase-4's h+-1 row reads hit that XCD's L2.
// ---------------------------------------------------------------------------
__global__ __launch_bounds__(256, 4) void fused(const float* __restrict__ x,
                                                const short* __restrict__ Abf,
                                                const float* __restrict__ w7,
                                                float* __restrict__ out) {
    __shared__ __align__(16) char smem[132 * LDS_STRIDE * 2];  // 19008 B
    short*    xsT = (short*)smem;      // [132][LDS_STRIDE] bf16, phases 1-2
    unsigned* xsW = (unsigned*)smem;   // dword view, stride 36
    short*    t3b = (short*)smem;      // [CC][T3B_STRIDE] bf16, phases 3-4

    const int bid = blockIdx.x;
    const int nh  = ((bid & 7) << 8) | (bid >> 3);   // XCD-contiguous h
    const int n   = nh >> 7;
    const int h   = nh & (HH - 1);
    const int tid = threadIdx.x;

    // ---- Phase 1: each thread owns ci-pair cp and w-strip wqg*16..+15 ----
    const float* xbase = x + (((size_t)n * CC) * HH + h) * WW;
    {
        const int cp  = tid & 31;       // ci pair: rows 2cp, 2cp+1
        const int wqg = tid >> 5;       // 0..7 -> w = wqg*16 .. +15
        const float* r0 = xbase + (size_t)(2 * cp) * (HH * WW);
        const float* r1 = r0 + HH * WW;
        #pragma unroll
        for (int q = 0; q < 4; ++q) {
            int wq = wqg * 4 + q;
            float4 a = *(const float4*)(r0 + wq * 4);
            float4 b = *(const float4*)(r1 + wq * 4);
            int wp = wq * 4 + 2;
            xsW[(wp + 0) * 36 + cp] = pack2bf(a.x, b.x);
            xsW[(wp + 1) * 36 + cp] = pack2bf(a.y, b.y);
            xsW[(wp + 2) * 36 + cp] = pack2bf(a.z, b.z);
            xsW[(wp + 3) * 36 + cp] = pack2bf(a.w, b.w);
        }
        if (tid < 128) {    // zero pad rows wp in {0,1,130,131}
            int wpi = tid >> 5;
            int wpz = (wpi < 2) ? wpi : 128 + wpi;
            xsW[wpz * 36 + (tid & 31)] = 0u;
        }
    }
    __syncthreads();

    // ---- Phase 2: MFMA ----
    const int W    = tid >> 6;       // wave id -> co-tile
    const int lane = tid & 63;
    const int lm   = lane & 15;
    const int g    = lane >> 4;

    floatx4 acc[8];
    #pragma unroll
    for (int nt = 0; nt < 8; ++nt) acc[nt] = (floatx4){0.f, 0.f, 0.f, 0.f};

    const short* arow = Abf + (W * 16 + lm) * 320;

    for (int ks = 0; ks < 10; ++ks) {
        const int kbase = ks * 32 + g * 8;
        const int tap   = kbase >> 6;
        const int cib   = kbase & 63;

        short8 a = *(const short8*)(arow + kbase);
        #pragma unroll
        for (int nt = 0; nt < 8; ++nt) {
            int wp = nt * 16 + lm + tap;
            short8 b = *(const short8*)&xsT[wp * LDS_STRIDE + cib];
            acc[nt] = __builtin_amdgcn_mfma_f32_16x16x32_bf16(a, b, acc[nt], 0, 0, 0);
        }
    }
    __syncthreads();   // xsT dead; t3b aliases it

    // ---- Phase 3: epilogue to LDS (bf16) ----
    #pragma unroll
    for (int nt = 0; nt < 8; ++nt) {
        #pragma unroll
        for (int r = 0; r < 4; ++r) {
            int co = W * 16 + g * 4 + r;
            t3b[co * T3B_STRIDE + nt * 16 + lm] = f2bf(acc[nt][r]);
        }
    }
    __syncthreads();

    // ---- Phase 4: combine, 4 outputs/thread, 8 iterations ----
    float* orow = out + (((size_t)n * CC) * HH + h) * WW;
    #pragma unroll
    for (int it = 0; it < 8; ++it) {
        const int item = it * 256 + tid;
        const int flat = item * 4;          // c*128 + w0
        const int w0   = flat & (WW - 1);
        const int c    = flat >> 7;
        const float* xb = x + ((size_t)(n * CC + c) * HH) * WW;

        float win[3][12];
        #pragma unroll
        for (int r = 0; r < 3; ++r) {
            int hh = h + r - 1;
            bool hok = (unsigned)hh < HH;
            #pragma unroll
            for (int q = 0; q < 3; ++q) {
                int cb = w0 - 4 + q * 4;
                float4 v = make_float4(0.f, 0.f, 0.f, 0.f);
                if (hok && (unsigned)cb < WW)
                    v = *(const float4*)(xb + hh * WW + cb);
                win[r][q * 4 + 0] = v.x; win[r][q * 4 + 1] = v.y;
                win[r][q * 4 + 2] = v.z; win[r][q * 4 + 3] = v.w;
            }
        }
        // w==0 wrap: rhs cols 125, 127 (j=2 -> col 129 -> 0 via pad).
        float wrap0[3] = {0.f, 0.f, 0.f}, wrap1[3] = {0.f, 0.f, 0.f};
        if (w0 == 0) {
            #pragma unroll
            for (int r = 0; r < 3; ++r) {
                int hh = h + r - 1;
                if ((unsigned)hh < HH) {
                    wrap0[r] = xb[hh * WW + 125];
                    wrap1[r] = xb[hh * WW + 127];
                }
            }
        }
        float wc[9];
        #pragma unroll
        for (int t = 0; t < 9; ++t) wc[t] = w7[c * 9 + t];

        ushort4 tv = *(const ushort4*)&t3b[c * T3B_STRIDE + w0];
        float t3v[4] = {bf2f(tv.x), bf2f(tv.y), bf2f(tv.z), bf2f(tv.w)};

        float res[4];
        #pragma unroll
        for (int e = 0; e < 4; ++e) {
            float a = 0.f;
            #pragma unroll
            for (int j = 0; j < 3; ++j) {
                #pragma unroll
                for (int i = 0; i < 3; ++i) {
                    float lhs = win[1][e + 2 * i + 2];        // col w+2(i-1)
                    float rhs;
                    if (e == 0 && w0 == 0)
                        rhs = (j == 0) ? wrap0[i] : ((j == 1) ? wrap1[i] : 0.f);
                    else
                        rhs = win[i][e + 2 * j + 1];          // col w+2j-3
                    a = fmaf(wc[j * 3 + i], fmaxf(lhs, rhs), a);
                }
            }
            res[e] = a;
        }
        float4 o;
        o.x = res[0] * t3v[0]; o.y = res[1] * t3v[1];
        o.z = res[2] * t3v[2]; o.w = res[3] * t3v[3];
        *(float4*)(orow + (size_t)c * (HH * WW) + w0) = o;
    }
}

extern "C" void kernel_launch(void* const* d_in, const int* in_sizes, int n_in,
                              void* d_out, int out_size, void* d_ws, size_t ws_size,
                              hipStream_t stream) {
    const float* x  = (const float*)d_in[0];
    const float* w3 = (const float*)d_in[1];
    const float* w7 = (const float*)d_in[2];
    float* out = (float*)d_out;

    short* Abf = (short*)d_ws;   // 40 KiB bf16 weights

    prep_w<<<(CC * CC * 5 + 255) / 256, 256, 0, stream>>>(w3, Abf);
    fused<<<NN * HH, 256, 0, stream>>>(x, Abf, w7, out);
}

// Round 6
// 146.782 us; speedup vs baseline: 1.0802x; 1.0489x over previous
//
#include <hip/hip_runtime.h>

// Problem constants (frozen by the reference)
#define NN 16
#define CC 64
#define HH 128
#define WW 128

#define LDS_STRIDE 72    // bf16 elems per xsT row (144 B; dword stride 36)
#define T3B_STRIDE 132   // bf16 elems per t3b row (264 B, 8B-aligned rows)

typedef __attribute__((ext_vector_type(8))) short short8;   // bf16x8 (4 VGPRs)
typedef __attribute__((ext_vector_type(4))) float floatx4;  // MFMA C/D

__device__ __forceinline__ short f2bf(float f) {
    union { float f; unsigned u; } v; v.f = f;
    unsigned r = v.u + 0x7fffu + ((v.u >> 16) & 1u);
    return (short)(r >> 16);
}
__device__ __forceinline__ unsigned pack2bf(float lo, float hi) {
    union { float f; unsigned u; } a, b; a.f = lo; b.f = hi;
    unsigned ra = a.u + 0x7fffu + ((a.u >> 16) & 1u);
    unsigned rb = b.u + 0x7fffu + ((b.u >> 16) & 1u);
    return (ra >> 16) | (rb & 0xffff0000u);
}
__device__ __forceinline__ float bf2f(unsigned short u) {
    union { unsigned u; float f; } v; v.u = ((unsigned)u) << 16;
    return v.f;
}

// ---------------------------------------------------------------------------
// Kernel 0: w3 (co, ci, 1, 5) fp32 -> Abf[co][kk] bf16, kk = tap*64 + ci.
// Also zeroes the 256 B zero-page used by fused's OOB window loads
// (d_ws is re-poisoned to 0xAA before every launch, so rewrite every call).
// ---------------------------------------------------------------------------
__global__ __launch_bounds__(256) void prep_w(const float* __restrict__ w3,
                                              short* __restrict__ Abf,
                                              float* __restrict__ zp) {
    int idx = blockIdx.x * 256 + threadIdx.x;
    if (idx < CC * CC * 5) {
        int tap = idx % 5;
        int ci  = (idx / 5) % CC;
        int co  = idx / (5 * CC);
        Abf[co * 320 + tap * 64 + ci] = f2bf(w3[idx]);
    }
    if (blockIdx.x == 0 && threadIdx.x < 64) zp[threadIdx.x] = 0.f;
}

// ---------------------------------------------------------------------------
// Fused kernel, one block per (n,h) row. LDS = 19008 B.
// Phase 1: stage x row transposed bf16, packed ci-pairs (conflict-free b32).
// Phase 2: MFMA GEMM D[co][w] = sum_kk A[co][kk] B[kk][w], kk = tap*64+ci.
// Phase 3: D -> LDS t3b (bf16, aliases dead xsT).
// Phase 4: combine, explicitly software-pipelined: 8 fully-unrolled
//   iterations over c = it*8 + (tid>>5), fixed w0 = (tid&31)*4.
//   - OOB window loads redirected to a zero page (stride 0) -> no branches.
//   - roll-wrap values (cols 125/127) fetched from lane tid|31 via __shfl.
//   - iteration it+1's 9 dwordx4 loads issued before computing it;
//     it=0 prefetched before the phase-3 barrier.
// ---------------------------------------------------------------------------
__global__ __launch_bounds__(256, 4) void fused(const float* __restrict__ x,
                                                const short* __restrict__ Abf,
                                                const float* __restrict__ w7,
                                                const float* __restrict__ zp,
                                                float* __restrict__ out) {
    __shared__ __align__(16) char smem[132 * LDS_STRIDE * 2];  // 19008 B
    short*    xsT = (short*)smem;      // [132][LDS_STRIDE] bf16, phases 1-2
    unsigned* xsW = (unsigned*)smem;   // dword view, stride 36
    short*    t3b = (short*)smem;      // [CC][T3B_STRIDE] bf16, phases 3-4

    const int bid = blockIdx.x;
    const int nh  = ((bid & 7) << 8) | (bid >> 3);   // XCD-contiguous h
    const int n   = nh >> 7;
    const int h   = nh & (HH - 1);
    const int tid = threadIdx.x;

    // ---- Phase 1: each thread owns ci-pair cp and w-strip wqg*16..+15 ----
    const float* xbase = x + (((size_t)n * CC) * HH + h) * WW;
    {
        const int cp  = tid & 31;       // ci pair: rows 2cp, 2cp+1
        const int wqg = tid >> 5;       // 0..7 -> w = wqg*16 .. +15
        const float* r0 = xbase + (size_t)(2 * cp) * (HH * WW);
        const float* r1 = r0 + HH * WW;
        #pragma unroll
        for (int q = 0; q < 4; ++q) {
            int wq = wqg * 4 + q;
            float4 a = *(const float4*)(r0 + wq * 4);
            float4 b = *(const float4*)(r1 + wq * 4);
            int wp = wq * 4 + 2;
            xsW[(wp + 0) * 36 + cp] = pack2bf(a.x, b.x);
            xsW[(wp + 1) * 36 + cp] = pack2bf(a.y, b.y);
            xsW[(wp + 2) * 36 + cp] = pack2bf(a.z, b.z);
            xsW[(wp + 3) * 36 + cp] = pack2bf(a.w, b.w);
        }
        if (tid < 128) {    // zero pad rows wp in {0,1,130,131}
            int wpi = tid >> 5;
            int wpz = (wpi < 2) ? wpi : 128 + wpi;
            xsW[wpz * 36 + (tid & 31)] = 0u;
        }
    }
    __syncthreads();

    // ---- Phase 2: MFMA ----
    const int W    = tid >> 6;       // wave id -> co-tile
    const int lane = tid & 63;
    const int lm   = lane & 15;
    const int g    = lane >> 4;

    floatx4 acc[8];
    #pragma unroll
    for (int nt = 0; nt < 8; ++nt) acc[nt] = (floatx4){0.f, 0.f, 0.f, 0.f};

    const short* arow = Abf + (W * 16 + lm) * 320;

    for (int ks = 0; ks < 10; ++ks) {
        const int kbase = ks * 32 + g * 8;
        const int tap   = kbase >> 6;
        const int cib   = kbase & 63;

        short8 a = *(const short8*)(arow + kbase);
        #pragma unroll
        for (int nt = 0; nt < 8; ++nt) {
            int wp = nt * 16 + lm + tap;
            short8 b = *(const short8*)&xsT[wp * LDS_STRIDE + cib];
            acc[nt] = __builtin_amdgcn_mfma_f32_16x16x32_bf16(a, b, acc[nt], 0, 0, 0);
        }
    }
    __syncthreads();   // xsT dead; t3b aliases it

    // ---- Phase 3: epilogue to LDS (bf16) ----
    #pragma unroll
    for (int nt = 0; nt < 8; ++nt) {
        #pragma unroll
        for (int r = 0; r < 4; ++r) {
            int co = W * 16 + g * 4 + r;
            t3b[co * T3B_STRIDE + nt * 16 + lm] = f2bf(acc[nt][r]);
        }
    }

    // ---- Phase 4 setup (before the barrier so it=0's loads complete
    //      during the barrier drain) ----
    const int w0  = (tid & 31) * 4;     // fixed per thread
    const int chi = tid >> 5;           // c = it*8 + chi
    const bool isw = (w0 == 0);
    const int src  = lane | 31;         // shfl source for wrap values

    const float* p[9];
    int s[9];
    const float* xb0 = x + (((size_t)(n * CC + chi)) * HH) * WW;
    #pragma unroll
    for (int r = 0; r < 3; ++r) {
        int hh = h + r - 1;
        bool hok = (unsigned)hh < HH;
        #pragma unroll
        for (int q = 0; q < 3; ++q) {
            int cb = w0 - 4 + q * 4;
            bool ok = hok && (unsigned)cb < WW;
            p[r * 3 + q] = ok ? (xb0 + (size_t)hh * WW + cb) : zp;
            s[r * 3 + q] = ok ? (8 * HH * WW) : 0;
        }
    }
    const float* wcp = w7 + chi * 9;
    int t3o = chi * T3B_STRIDE + w0;
    float* outp = out + ((((size_t)(n * CC + chi)) * HH + h) * WW) + w0;

    float4 cur[9];
    #pragma unroll
    for (int t = 0; t < 9; ++t) { cur[t] = *(const float4*)p[t]; p[t] += s[t]; }

    __syncthreads();

    // ---- Phase 4: combine, pipelined, fully unrolled ----
    #pragma unroll
    for (int it = 0; it < 8; ++it) {
        float4 nxt[9];
        if (it < 7) {
            #pragma unroll
            for (int t = 0; t < 9; ++t) { nxt[t] = *(const float4*)p[t]; p[t] += s[t]; }
        }

        // window view: win[r][q*4+k] = col w0-4+q*4+k of row h+r-1
        float win[3][12];
        #pragma unroll
        for (int r = 0; r < 3; ++r) {
            #pragma unroll
            for (int q = 0; q < 3; ++q) {
                float4 v = cur[r * 3 + q];
                win[r][q * 4 + 0] = v.x; win[r][q * 4 + 1] = v.y;
                win[r][q * 4 + 2] = v.z; win[r][q * 4 + 3] = v.w;
            }
        }
        // wrap values (w==0 roll): cols 125,127 live in lane tid|31's q=1 quad
        float wrap0[3], wrap1[3];
        #pragma unroll
        for (int r = 0; r < 3; ++r) {
            wrap0[r] = __shfl(win[r][5], src);
            wrap1[r] = __shfl(win[r][7], src);
        }

        float wc[9];
        #pragma unroll
        for (int t = 0; t < 9; ++t) wc[t] = wcp[t];

        ushort4 tv = *(const ushort4*)&t3b[t3o];
        float t3v[4] = {bf2f(tv.x), bf2f(tv.y), bf2f(tv.z), bf2f(tv.w)};

        float res[4];
        #pragma unroll
        for (int e = 0; e < 4; ++e) {
            float a = 0.f;
            #pragma unroll
            for (int j = 0; j < 3; ++j) {
                #pragma unroll
                for (int i = 0; i < 3; ++i) {
                    float lhs = win[1][e + 2 * i + 2];        // col w+2(i-1)
                    float rhs = win[i][e + 2 * j + 1];        // col w+2j-3
                    if (e == 0)
                        rhs = isw ? ((j == 0) ? wrap0[i]
                                   : (j == 1) ? wrap1[i] : 0.f)
                                  : rhs;
                    a = fmaf(wc[j * 3 + i], fmaxf(lhs, rhs), a);
                }
            }
            res[e] = a;
        }
        float4 o;
        o.x = res[0] * t3v[0]; o.y = res[1] * t3v[1];
        o.z = res[2] * t3v[2]; o.w = res[3] * t3v[3];
        *(float4*)outp = o;

        // advance per-iteration state
        wcp  += 8 * 9;
        t3o  += 8 * T3B_STRIDE;
        outp += (size_t)8 * HH * WW;
        #pragma unroll
        for (int t = 0; t < 9; ++t) cur[t] = nxt[t];
    }
}

extern "C" void kernel_launch(void* const* d_in, const int* in_sizes, int n_in,
                              void* d_out, int out_size, void* d_ws, size_t ws_size,
                              hipStream_t stream) {
    const float* x  = (const float*)d_in[0];
    const float* w3 = (const float*)d_in[1];
    const float* w7 = (const float*)d_in[2];
    float* out = (float*)d_out;

    short* Abf = (short*)d_ws;                    // 40960 B bf16 weights
    float* zp  = (float*)((char*)d_ws + 40960);   // 256 B zero page

    prep_w<<<(CC * CC * 5 + 255) / 256, 256, 0, stream>>>(w3, Abf, zp);
    fused<<<NN * HH, 256, 0, stream>>>(x, Abf, w7, zp, out);
}